// Round 6
// baseline (1427.674 us; speedup 1.0000x reference)
//
#include <hip/hip_runtime.h>
#include <math.h>

#define NN 50000
#define NE 600000
#define D  128

typedef __attribute__((ext_vector_type(8))) short bf16x8;
typedef __attribute__((ext_vector_type(4))) float f32x4;

__device__ __forceinline__ short f2bf(float f) {
    union { float f; unsigned u; } c; c.f = f;
    unsigned r = c.u + 0x7fff + ((c.u >> 16) & 1);   // RNE
    return (short)(r >> 16);
}

__device__ __forceinline__ bf16x8 pack8(const float* p) {
    float4 lo = *(const float4*)p;
    float4 hi = *(const float4*)(p + 4);
    bf16x8 r;
    r[0] = f2bf(lo.x); r[1] = f2bf(lo.y); r[2] = f2bf(lo.z); r[3] = f2bf(lo.w);
    r[4] = f2bf(hi.x); r[5] = f2bf(hi.y); r[6] = f2bf(hi.z); r[7] = f2bf(hi.w);
    return r;
}

// ---------------------------------------------------------------------------
// Pre-kernel: WT[n][k] = bf16(W[k][n]) (512x128), WeT[n][k] = bf16(We[k][n])
// ---------------------------------------------------------------------------
__global__ __launch_bounds__(256) void transpose_cast_kernel(
    const float* __restrict__ W, const float* __restrict__ We,
    short* __restrict__ WT, short* __restrict__ WeT)
{
    int idx = blockIdx.x * 256 + threadIdx.x;
    if (idx < 512 * 128) {
        int n = idx >> 7, k = idx & 127;
        WT[idx] = f2bf(W[k * 512 + n]);
    }
    if (idx < 128 * 128) {
        int n = idx >> 7, k = idx & 127;
        WeT[idx] = f2bf(We[k * 128 + n]);
    }
}

// ---------------------------------------------------------------------------
// Node proj (MFMA, swapped operands: D[dim][node]).
// Wave w computes output section [w*128, w*128+128) for 16 nodes.
// Lane (lr=l&15, lk=l>>4): node m0+lr; dims nf*16 + lk*4 + 0..3 per frag.
// A = WT rows (dims), B = X rows (nodes). Stores are float4.
// ---------------------------------------------------------------------------
__global__ __launch_bounds__(256, 4) void node_proj_kernel(
    const float* __restrict__ X,
    const short* __restrict__ WT,     // [512][128] bf16
    const float* __restrict__ bias,
    float* __restrict__ out_h,
    float* __restrict__ Qp, float* __restrict__ Kp, float* __restrict__ Vp)
{
    const int tid = threadIdx.x;
    const int w   = tid >> 6;
    const int l   = tid & 63;
    const int lr  = l & 15;
    const int lk  = l >> 4;
    const int m0  = blockIdx.x * 16;        // grid 3125, exact
    const int n0  = w * 128;                // output section base

    // B-frags: this lane's node row, all K
    bf16x8 bfrag[4];
    const float* xrow = X + (size_t)(m0 + lr) * D + lk * 8;
#pragma unroll
    for (int ks = 0; ks < 4; ++ks) bfrag[ks] = pack8(xrow + ks * 32);

    f32x4 acc[8];
#pragma unroll
    for (int nf = 0; nf < 8; ++nf) acc[nf] = (f32x4){0.f, 0.f, 0.f, 0.f};

#pragma unroll
    for (int nf = 0; nf < 8; ++nf) {
        const short* abase = WT + (size_t)(n0 + nf * 16 + lr) * D + lk * 8;
#pragma unroll
        for (int ks = 0; ks < 4; ++ks) {
            bf16x8 afrag = *(const bf16x8*)(abase + ks * 32);
            acc[nf] = __builtin_amdgcn_mfma_f32_16x16x32_bf16(afrag, bfrag[ks], acc[nf], 0, 0, 0);
        }
    }

    float* dst = (w == 0) ? out_h : (w == 1) ? Qp : (w == 2) ? Kp : Vp;
    const int m = m0 + lr;
#pragma unroll
    for (int nf = 0; nf < 8; ++nf) {
        int dl = nf * 16 + lk * 4;          // dim within section
        float4 bi = *(const float4*)&bias[n0 + dl];
        float4 r;
        r.x = acc[nf][0] + bi.x;
        r.y = acc[nf][1] + bi.y;
        r.z = acc[nf][2] + bi.z;
        r.w = acc[nf][3] + bi.w;
        *(float4*)&dst[(size_t)m * D + dl] = r;
    }
}

// ---------------------------------------------------------------------------
// Edge kernel (MFMA, swapped operands: D[dim][edge]).
// Lane owns ONE edge (e0+lr) and 32 dims in float4 groups.
// Gathers q/k/v and the atomic scatter are all float4-granular.
// ---------------------------------------------------------------------------
__global__ __launch_bounds__(256, 4) void edge_kernel(
    const float* __restrict__ EF,
    const int*   __restrict__ snd,
    const int*   __restrict__ rcv,
    const short* __restrict__ WeT,    // [128][128] bf16
    const float* __restrict__ web,
    const float* __restrict__ Qp, const float* __restrict__ Kp,
    const float* __restrict__ Vp,
    float* __restrict__ out)
{
    const int tid = threadIdx.x;
    const int w   = tid >> 6;
    const int l   = tid & 63;
    const int lr  = l & 15;
    const int lk  = l >> 4;
    const int e0  = blockIdx.x * 64 + w * 16;   // grid 9375, exact
    const int e   = e0 + lr;                    // this lane's edge

    const int s = snd[e];
    const int r = rcv[e];

    // B-frags: this lane's edge-feature row, all K
    bf16x8 bfrag[4];
    const float* erow = EF + (size_t)e * D + lk * 8;
#pragma unroll
    for (int ks = 0; ks < 4; ++ks) bfrag[ks] = pack8(erow + ks * 32);

    f32x4 acc[8];
#pragma unroll
    for (int nf = 0; nf < 8; ++nf) acc[nf] = (f32x4){0.f, 0.f, 0.f, 0.f};

#pragma unroll
    for (int nf = 0; nf < 8; ++nf) {
        const short* abase = WeT + (size_t)(nf * 16 + lr) * D + lk * 8;
#pragma unroll
        for (int ks = 0; ks < 4; ++ks) {
            bf16x8 afrag = *(const bf16x8*)(abase + ks * 32);
            acc[nf] = __builtin_amdgcn_mfma_f32_16x16x32_bf16(afrag, bfrag[ks], acc[nf], 0, 0, 0);
        }
    }

    // epilogue: per frag, float4 gathers + gate + 4 atomics
    const float* qrow = Qp + (size_t)r * D;
    const float* krow = Kp + (size_t)s * D;
    const float* vrow = Vp + (size_t)s * D;
    float* orow = out + (size_t)r * D;
#pragma unroll
    for (int nf = 0; nf < 8; ++nf) {
        int dl = nf * 16 + lk * 4;
        float4 q  = *(const float4*)&qrow[dl];
        float4 kk = *(const float4*)&krow[dl];
        float4 v  = *(const float4*)&vrow[dl];
        float4 wb = *(const float4*)&web[dl];
        float x0 = acc[nf][0] + q.x + kk.x + wb.x;
        float x1 = acc[nf][1] + q.y + kk.y + wb.y;
        float x2 = acc[nf][2] + q.z + kk.z + wb.z;
        float x3 = acc[nf][3] + q.w + kk.w + wb.w;
        float g0 = 1.f / (1.f + __expf(-x0));
        float g1 = 1.f / (1.f + __expf(-x1));
        float g2 = 1.f / (1.f + __expf(-x2));
        float g3 = 1.f / (1.f + __expf(-x3));
        atomicAdd(orow + dl + 0, g0 * v.x);
        atomicAdd(orow + dl + 1, g1 * v.y);
        atomicAdd(orow + dl + 2, g2 * v.z);
        atomicAdd(orow + dl + 3, g3 * v.w);
    }
}

extern "C" void kernel_launch(void* const* d_in, const int* in_sizes, int n_in,
                              void* d_out, int out_size, void* d_ws, size_t ws_size,
                              hipStream_t stream)
{
    const float* X   = (const float*)d_in[0];
    const int*   snd = (const int*)  d_in[1];
    const int*   rcv = (const int*)  d_in[2];
    const float* EF  = (const float*)d_in[3];
    const float* W   = (const float*)d_in[4];
    const float* Wb  = (const float*)d_in[5];
    const float* We  = (const float*)d_in[6];
    const float* Web = (const float*)d_in[7];
    float* out = (float*)d_out;

    float* Qp = (float*)d_ws;                        // [NN][128] f32
    float* Kp = Qp + (size_t)NN * D;
    float* Vp = Kp + (size_t)NN * D;
    short* WT  = (short*)(Vp + (size_t)NN * D);      // [512][128] bf16
    short* WeT = WT + 512 * 128;                     // [128][128] bf16

    transpose_cast_kernel<<<256, 256, 0, stream>>>(W, We, WT, WeT);

    node_proj_kernel<<<NN / 16, 256, 0, stream>>>(X, WT, Wb, out, Qp, Kp, Vp);

    edge_kernel<<<NE / 64, 256, 0, stream>>>(EF, snd, rcv, WeT, Web, Qp, Kp, Vp, out);
}